// Round 2
// baseline (344.591 us; speedup 1.0000x reference)
//
#include <hip/hip_runtime.h>

#define B_ 8
#define N_ 2048
#define FIN_ 512
#define FOUT_ 512

typedef __attribute__((ext_vector_type(8))) short short8;
typedef __attribute__((ext_vector_type(4))) float floatx4;
typedef __attribute__((ext_vector_type(4))) unsigned short ushortx4;
typedef __attribute__((ext_vector_type(8))) unsigned short ushortx8;

__device__ inline unsigned short f2bf(float f) {
    union { float f; unsigned int u; } x; x.f = f;
    unsigned int r = x.u + 0x7FFFu + ((x.u >> 16) & 1u);  // RNE
    return (unsigned short)(r >> 16);
}

__device__ inline void glds16(const void* g, void* l) {
    __builtin_amdgcn_global_load_lds(
        (const __attribute__((address_space(1))) void*)g,
        (__attribute__((address_space(3))) void*)l, 16, 0, 0);
}

// --- 1) dinv[b*N+i] = rsqrt(1 + sum_j A[b,i,j]) ------------------------------
__global__ __launch_bounds__(256) void degree_kernel(const float* __restrict__ A,
                                                     float* __restrict__ dinv) {
    int row = blockIdx.x;                 // b*N + i
    const float4* A4 = (const float4*)(A + (size_t)row * N_);
    int t = threadIdx.x;
    float4 v0 = A4[t];
    float4 v1 = A4[t + 256];
    float s = v0.x + v0.y + v0.z + v0.w + v1.x + v1.y + v1.z + v1.w;
#pragma unroll
    for (int off = 32; off > 0; off >>= 1) s += __shfl_down(s, off, 64);
    __shared__ float red[4];
    if ((t & 63) == 0) red[t >> 6] = s;
    __syncthreads();
    if (t == 0) dinv[row] = rsqrtf(red[0] + red[1] + red[2] + red[3] + 1.0f);
}

// --- 2) Lbf[b,i,j] = bf16((A[b,i,j] + (i==j)) * dinv_i * dinv_j) -------------
__global__ __launch_bounds__(256) void scaleL_kernel(const float* __restrict__ A,
                                                     const float* __restrict__ dinv,
                                                     unsigned short* __restrict__ Lbf) {
    size_t e0 = ((size_t)blockIdx.x * 256 + threadIdx.x) * 8;
    int b   = (int)(e0 >> 22);            // N*N = 2^22
    int rem = (int)(e0 & ((1u << 22) - 1));
    int i   = rem >> 11;                  // N = 2^11
    int j0  = rem & 2047;
    float di = dinv[b * N_ + i];
    const float* dj = dinv + b * N_ + j0;
    float4 a0 = *(const float4*)(A + e0);
    float4 a1 = *(const float4*)(A + e0 + 4);
    float4 d0 = *(const float4*)(dj);
    float4 d1 = *(const float4*)(dj + 4);
    float av[8] = {a0.x, a0.y, a0.z, a0.w, a1.x, a1.y, a1.z, a1.w};
    float dv[8] = {d0.x, d0.y, d0.z, d0.w, d1.x, d1.y, d1.z, d1.w};
    int dd = i - j0;
    if (dd >= 0 && dd < 8) av[dd] += 1.0f;
    ushortx8 p;
#pragma unroll
    for (int r = 0; r < 8; ++r) p[r] = f2bf(av[r] * di * dv[r]);
    *(ushortx8*)(Lbf + e0) = p;
}

// --- 3a) X -> bf16 -----------------------------------------------------------
__global__ __launch_bounds__(256) void castX_kernel(const float* __restrict__ X,
                                                    unsigned short* __restrict__ Xbf) {
    size_t e0 = ((size_t)blockIdx.x * 256 + threadIdx.x) * 8;
    float4 a0 = *(const float4*)(X + e0);
    float4 a1 = *(const float4*)(X + e0 + 4);
    float av[8] = {a0.x, a0.y, a0.z, a0.w, a1.x, a1.y, a1.z, a1.w};
    ushortx8 p;
#pragma unroll
    for (int r = 0; r < 8; ++r) p[r] = f2bf(av[r]);
    *(ushortx8*)(Xbf + e0) = p;
}

// --- 3b) Wt[n][k] = bf16(W[k][n]) -------------------------------------------
__global__ __launch_bounds__(256) void transposeW_kernel(const float* __restrict__ W,
                                                         unsigned short* __restrict__ Wt) {
    __shared__ float tile[32][33];
    int bx = blockIdx.x * 32;   // F_OUT block
    int by = blockIdx.y * 32;   // F_IN block
    int tx = threadIdx.x, ty = threadIdx.y;   // 32 x 8
#pragma unroll
    for (int r = 0; r < 32; r += 8)
        tile[ty + r][tx] = W[(size_t)(by + ty + r) * FOUT_ + bx + tx];
    __syncthreads();
#pragma unroll
    for (int r = 0; r < 32; r += 8)
        Wt[(size_t)(bx + ty + r) * FIN_ + by + tx] = f2bf(tile[tx][ty + r]);
}

// --- 4) GEMM1: x^T = (Xbf @ Wt^T + b)^T, bf16, coalesced via LDS transpose ---
// 128x128 tile, 4 waves x (4x4) 16x16x32 MFMA, BK=32, K=512 (16 iters).
// Epilogue: C-tile -> LDS (bf16, ld=136) -> XwT[b][f][node] 128B-chunk stores.
__global__ __launch_bounds__(256) void gemm1_kernel(
    const unsigned short* __restrict__ Abase,   // Xbf [16384][512]
    const unsigned short* __restrict__ Btbase,  // Wt  [512][512]
    unsigned short* __restrict__ XwT,           // [8][512][2048]
    const float* __restrict__ bias) {
    __shared__ __align__(16) char smem[34816];  // K-loop: 16 KB; epi: 128x136 bf16
    char* As = smem;          // 128 x 32 bf16 = 8 KB
    char* Bs = smem + 8192;   // 128 x 32 bf16 = 8 KB

    int t = threadIdx.x;
    int lane = t & 63;
    int wave = t >> 6;
    int wr = wave >> 1, wc = wave & 1;
    int q = lane >> 4, m = lane & 15;
    int n0 = blockIdx.x * 128;   // FOUT block
    int m0 = blockIdx.y * 128;   // node block (never straddles a batch)

    int srow = t >> 2;           // staging row (8 elems per thread)
    int skk = (t & 3) * 8;

    floatx4 acc[4][4];
#pragma unroll
    for (int mi = 0; mi < 4; ++mi)
#pragma unroll
        for (int ni = 0; ni < 4; ++ni)
            acc[mi][ni] = (floatx4){0.f, 0.f, 0.f, 0.f};

    const unsigned short* gA  = Abase + (size_t)(m0 + srow) * FIN_ + skk;
    const unsigned short* gA2 = Abase + (size_t)(m0 + srow + 64) * FIN_ + skk;
    const unsigned short* gB  = Btbase + (size_t)(srow) * FIN_ + skk;        // n0=0..384
    const unsigned short* gB2 = Btbase + (size_t)(srow + 64) * FIN_ + skk;
    gB  += (size_t)n0 * FIN_;
    gB2 += (size_t)n0 * FIN_;
    char* lA  = As + wave * 1024;
    char* lA2 = As + 4096 + wave * 1024;
    char* lB  = Bs + wave * 1024;
    char* lB2 = Bs + 4096 + wave * 1024;

    for (int kt = 0; kt < FIN_ / 32; ++kt) {
        glds16(gA, lA);
        glds16(gA2, lA2);
        glds16(gB, lB);
        glds16(gB2, lB2);
        gA += 32; gA2 += 32; gB += 32; gB2 += 32;
        __syncthreads();

        short8 af[4], bfr[4];
#pragma unroll
        for (int mi = 0; mi < 4; ++mi)
            af[mi] = *(const short8*)(As + (wr * 64 + mi * 16 + m) * 64 + q * 16);
#pragma unroll
        for (int ni = 0; ni < 4; ++ni)
            bfr[ni] = *(const short8*)(Bs + (wc * 64 + ni * 16 + m) * 64 + q * 16);
#pragma unroll
        for (int mi = 0; mi < 4; ++mi)
#pragma unroll
            for (int ni = 0; ni < 4; ++ni)
                acc[mi][ni] = __builtin_amdgcn_mfma_f32_16x16x32_bf16(
                    af[mi], bfr[ni], acc[mi][ni], 0, 0, 0);
        __syncthreads();
    }

    // ---- epilogue: transpose through LDS, coalesced bf16 stores ----
    unsigned short* T = (unsigned short*)smem;  // [128][136]
#pragma unroll
    for (int mi = 0; mi < 4; ++mi) {
        int row = wr * 64 + mi * 16 + q * 4;       // node-local (4 consecutive)
#pragma unroll
        for (int ni = 0; ni < 4; ++ni) {
            int col = wc * 64 + ni * 16 + m;       // f-local
            float bv = bias[n0 + col];
            ushortx4 pk;
#pragma unroll
            for (int r = 0; r < 4; ++r) pk[r] = f2bf(acc[mi][ni][r] + bv);
            *(ushortx4*)(T + col * 136 + row) = pk;
        }
    }
    __syncthreads();
    int f  = t >> 1;             // 0..127
    int c0 = (t & 1) * 64;       // node half
    int bb = m0 >> 11;
    int node0 = (m0 & 2047) + c0;
    unsigned short* dst = XwT + ((size_t)bb * FOUT_ + n0 + f) * N_ + node0;
    const unsigned short* src = T + f * 136 + c0;
#pragma unroll
    for (int u = 0; u < 8; ++u)
        *(ushortx8*)(dst + u * 8) = *(const ushortx8*)(src + u * 8);
}

// --- 5) GEMM2: out[b] = Lbf[b] @ x[b], 64x128 tile, fp32 out ----------------
// 4 waves, each 32x64 (2x4 MFMA frags). K=2048 (64 iters). Grid 32x4x8 = 1024.
__global__ __launch_bounds__(256) void gemm2_kernel(
    const unsigned short* __restrict__ Lbf,   // [8][2048][2048]
    const unsigned short* __restrict__ XwT,   // [8][512][2048]  (= x^T = B^T)
    float* __restrict__ out) {                // [8][2048][512]
    __shared__ __align__(16) char smem[12288];
    char* As = smem;          // 64 x 32 bf16 = 4 KB
    char* Bs = smem + 4096;   // 128 x 32 bf16 = 8 KB

    int t = threadIdx.x;
    int lane = t & 63;
    int wave = t >> 6;
    int wr = wave & 1;        // 2 row-groups of 32
    int wc = wave >> 1;       // 2 col-groups of 64
    int q = lane >> 4, m = lane & 15;
    int n0 = blockIdx.x * 128;   // FOUT block
    int m0 = blockIdx.y * 64;    // node block
    int b = blockIdx.z;
    const unsigned short* Ab = Lbf + (size_t)b * N_ * N_;
    const unsigned short* Bb = XwT + (size_t)b * FOUT_ * N_;

    int srow = t >> 2;
    int skk = (t & 3) * 8;

    floatx4 acc[2][4];
#pragma unroll
    for (int mi = 0; mi < 2; ++mi)
#pragma unroll
        for (int ni = 0; ni < 4; ++ni)
            acc[mi][ni] = (floatx4){0.f, 0.f, 0.f, 0.f};

    const unsigned short* gA  = Ab + (size_t)(m0 + srow) * N_ + skk;       // 64 rows
    const unsigned short* gB  = Bb + (size_t)(n0 + srow) * N_ + skk;       // rows 0-63
    const unsigned short* gB2 = Bb + (size_t)(n0 + srow + 64) * N_ + skk;  // rows 64-127
    char* lA  = As + wave * 1024;
    char* lB  = Bs + wave * 1024;
    char* lB2 = Bs + 4096 + wave * 1024;

    for (int kt = 0; kt < N_ / 32; ++kt) {
        glds16(gA, lA);
        glds16(gB, lB);
        glds16(gB2, lB2);
        gA += 32; gB += 32; gB2 += 32;
        __syncthreads();

        short8 af[2], bfr[4];
#pragma unroll
        for (int mi = 0; mi < 2; ++mi)
            af[mi] = *(const short8*)(As + (wr * 32 + mi * 16 + m) * 64 + q * 16);
#pragma unroll
        for (int ni = 0; ni < 4; ++ni)
            bfr[ni] = *(const short8*)(Bs + (wc * 64 + ni * 16 + m) * 64 + q * 16);
#pragma unroll
        for (int mi = 0; mi < 2; ++mi)
#pragma unroll
            for (int ni = 0; ni < 4; ++ni)
                acc[mi][ni] = __builtin_amdgcn_mfma_f32_16x16x32_bf16(
                    af[mi], bfr[ni], acc[mi][ni], 0, 0, 0);
        __syncthreads();
    }

    // C/D layout: col = lane&15, row = (lane>>4)*4 + reg
    float* C = out + (size_t)b * N_ * FOUT_;
#pragma unroll
    for (int mi = 0; mi < 2; ++mi) {
        int rowb = m0 + wr * 32 + mi * 16 + q * 4;
#pragma unroll
        for (int ni = 0; ni < 4; ++ni) {
            int col = n0 + wc * 64 + ni * 16 + m;
#pragma unroll
            for (int r = 0; r < 4; ++r)
                C[(size_t)(rowb + r) * FOUT_ + col] = acc[mi][ni][r];
        }
    }
}

extern "C" void kernel_launch(void* const* d_in, const int* in_sizes, int n_in,
                              void* d_out, int out_size, void* d_ws, size_t ws_size,
                              hipStream_t stream) {
    const float* X    = (const float*)d_in[0];   // [8,2048,512]
    const float* A    = (const float*)d_in[1];   // [8,2048,2048]
    const float* W    = (const float*)d_in[2];   // [512,512]
    const float* bias = (const float*)d_in[3];   // [512]
    float* out = (float*)d_out;                  // [8,2048,512] fp32
    char* ws = (char*)d_ws;

    float* dinv          = (float*)(ws);                              // 64 KB
    unsigned short* Xbf  = (unsigned short*)(ws + (1u << 16));        // 16 MB
    unsigned short* Wt   = (unsigned short*)(ws + (1u << 16) + 16777216u);           // 512 KB
    unsigned short* XwT  = (unsigned short*)(ws + (1u << 16) + 16777216u + 524288u); // 16 MB
    unsigned short* Lbf  = (unsigned short*)(ws + (1u << 16) + 16777216u + 524288u + 16777216u); // 64 MB

    degree_kernel<<<B_ * N_, 256, 0, stream>>>(A, dinv);
    scaleL_kernel<<<(B_ * (size_t)N_ * N_) / 2048, 256, 0, stream>>>(A, dinv, Lbf);
    castX_kernel<<<((size_t)B_ * N_ * FIN_) / 2048, 256, 0, stream>>>(X, Xbf);
    transposeW_kernel<<<dim3(FOUT_ / 32, FIN_ / 32), dim3(32, 8), 0, stream>>>(W, Wt);

    gemm1_kernel<<<dim3(FOUT_ / 128, (B_ * N_) / 128), 256, 0, stream>>>(
        Xbf, Wt, XwT, bias);

    gemm2_kernel<<<dim3(FOUT_ / 128, N_ / 64, B_), 256, 0, stream>>>(
        Lbf, XwT, out);
}

// Round 3
// 344.166 us; speedup vs baseline: 1.0012x; 1.0012x over previous
//
#include <hip/hip_runtime.h>

#define B_ 8
#define N_ 2048
#define FIN_ 512
#define FOUT_ 512

typedef __attribute__((ext_vector_type(8))) short short8;
typedef __attribute__((ext_vector_type(4))) float floatx4;
typedef __attribute__((ext_vector_type(4))) unsigned short ushortx4;
typedef __attribute__((ext_vector_type(8))) unsigned short ushortx8;

__device__ inline unsigned short f2bf(float f) {
    union { float f; unsigned int u; } x; x.f = f;
    unsigned int r = x.u + 0x7FFFu + ((x.u >> 16) & 1u);  // RNE
    return (unsigned short)(r >> 16);
}

__device__ inline void glds16(const void* g, void* l) {
    __builtin_amdgcn_global_load_lds(
        (const __attribute__((address_space(1))) void*)g,
        (__attribute__((address_space(3))) void*)l, 16, 0, 0);
}

// --- 1) dinv[b*N+i] = rsqrt(1 + sum_j A[b,i,j]) ------------------------------
__global__ __launch_bounds__(256) void degree_kernel(const float* __restrict__ A,
                                                     float* __restrict__ dinv) {
    int row = blockIdx.x;                 // b*N + i
    const float4* A4 = (const float4*)(A + (size_t)row * N_);
    int t = threadIdx.x;
    float4 v0 = A4[t];
    float4 v1 = A4[t + 256];
    float s = v0.x + v0.y + v0.z + v0.w + v1.x + v1.y + v1.z + v1.w;
#pragma unroll
    for (int off = 32; off > 0; off >>= 1) s += __shfl_down(s, off, 64);
    __shared__ float red[4];
    if ((t & 63) == 0) red[t >> 6] = s;
    __syncthreads();
    if (t == 0) dinv[row] = rsqrtf(red[0] + red[1] + red[2] + red[3] + 1.0f);
}

// --- 2) Lbf[b,i,j] = bf16((A[b,i,j] + (i==j)) * dinv_i * dinv_j) -------------
__global__ __launch_bounds__(256) void scaleL_kernel(const float* __restrict__ A,
                                                     const float* __restrict__ dinv,
                                                     unsigned short* __restrict__ Lbf) {
    size_t e0 = ((size_t)blockIdx.x * 256 + threadIdx.x) * 8;
    int b   = (int)(e0 >> 22);            // N*N = 2^22
    int rem = (int)(e0 & ((1u << 22) - 1));
    int i   = rem >> 11;                  // N = 2^11
    int j0  = rem & 2047;
    float di = dinv[b * N_ + i];
    const float* dj = dinv + b * N_ + j0;
    float4 a0 = *(const float4*)(A + e0);
    float4 a1 = *(const float4*)(A + e0 + 4);
    float4 d0 = *(const float4*)(dj);
    float4 d1 = *(const float4*)(dj + 4);
    float av[8] = {a0.x, a0.y, a0.z, a0.w, a1.x, a1.y, a1.z, a1.w};
    float dv[8] = {d0.x, d0.y, d0.z, d0.w, d1.x, d1.y, d1.z, d1.w};
    int dd = i - j0;
    if (dd >= 0 && dd < 8) av[dd] += 1.0f;
    ushortx8 p;
#pragma unroll
    for (int r = 0; r < 8; ++r) p[r] = f2bf(av[r] * di * dv[r]);
    *(ushortx8*)(Lbf + e0) = p;
}

// --- 3a) X -> bf16 -----------------------------------------------------------
__global__ __launch_bounds__(256) void castX_kernel(const float* __restrict__ X,
                                                    unsigned short* __restrict__ Xbf) {
    size_t e0 = ((size_t)blockIdx.x * 256 + threadIdx.x) * 8;
    float4 a0 = *(const float4*)(X + e0);
    float4 a1 = *(const float4*)(X + e0 + 4);
    float av[8] = {a0.x, a0.y, a0.z, a0.w, a1.x, a1.y, a1.z, a1.w};
    ushortx8 p;
#pragma unroll
    for (int r = 0; r < 8; ++r) p[r] = f2bf(av[r]);
    *(ushortx8*)(Xbf + e0) = p;
}

// --- 3b) Wt[n][k] = bf16(W[k][n]) -------------------------------------------
__global__ __launch_bounds__(256) void transposeW_kernel(const float* __restrict__ W,
                                                         unsigned short* __restrict__ Wt) {
    __shared__ float tile[32][33];
    int bx = blockIdx.x * 32;   // F_OUT block
    int by = blockIdx.y * 32;   // F_IN block
    int tx = threadIdx.x, ty = threadIdx.y;   // 32 x 8
#pragma unroll
    for (int r = 0; r < 32; r += 8)
        tile[ty + r][tx] = W[(size_t)(by + ty + r) * FOUT_ + bx + tx];
    __syncthreads();
#pragma unroll
    for (int r = 0; r < 32; r += 8)
        Wt[(size_t)(bx + ty + r) * FIN_ + by + tx] = f2bf(tile[tx][ty + r]);
}

// ============================================================================
// Swizzled LDS tile: rows of BK=64 bf16 (128 B = 8 chunks of 16 B).
// chunk' = chunk ^ (row & 7).  Staging: thread t of issue u lands at flat
// byte u*4096 + t*16 -> row = u*32 + (t>>3), chunk' = t&7, so it must FETCH
// global chunk c = (t&7) ^ ((t>>3)&7).  Fragment read for 16 consecutive
// rows then hits each bank exactly 2x (free).
// ============================================================================

// --- 4) GEMM1: x^T = (Xbf @ Wt^T + b)^T, 128x128 tile, BK=64, 8 iters -------
__global__ __launch_bounds__(256) void gemm1_kernel(
    const unsigned short* __restrict__ Abase,   // Xbf [16384][512]
    const unsigned short* __restrict__ Btbase,  // Wt  [512][512]
    unsigned short* __restrict__ XwT,           // [8][512][2048]
    const float* __restrict__ bias) {
    __shared__ __align__(16) char smem[34816];  // K-loop 32 KB; epi 128x136 bf16
    char* As = smem;            // 128 x 128 B (swizzled) = 16 KB
    char* Bs = smem + 16384;    // 128 x 128 B (swizzled) = 16 KB

    int t = threadIdx.x;
    int lane = t & 63;
    int wave = t >> 6;
    int wr = wave >> 1, wc = wave & 1;
    int q = lane >> 4, m = lane & 15;
    int n0 = blockIdx.x * 128;   // FOUT block
    int m0 = blockIdx.y * 128;   // node block

    // staging source mapping (see banner)
    int srow = t >> 3;                       // 0..31 per issue
    int scol = (((t & 7) ^ (srow & 7)) * 8); // global elem chunk start

    // fragment swizzle: row&7 == m&7 for all frag rows
    int x0 = ((q ^ (m & 7)) * 16);           // sub-slab 0 chunk byte
    int x1 = x0 ^ 64;                        // sub-slab 1 (chunk c^=4)

    floatx4 acc[4][4];
#pragma unroll
    for (int mi = 0; mi < 4; ++mi)
#pragma unroll
        for (int ni = 0; ni < 4; ++ni)
            acc[mi][ni] = (floatx4){0.f, 0.f, 0.f, 0.f};

    const unsigned short* gA = Abase + (size_t)(m0 + srow) * FIN_ + scol;
    const unsigned short* gB = Btbase + (size_t)(n0 + srow) * FIN_ + scol;
    char* lA = As + wave * 1024;
    char* lB = Bs + wave * 1024;

    for (int kt = 0; kt < FIN_ / 64; ++kt) {
#pragma unroll
        for (int u = 0; u < 4; ++u) {
            glds16(gA + (size_t)(u * 32) * FIN_, lA + u * 4096);
            glds16(gB + (size_t)(u * 32) * FIN_, lB + u * 4096);
        }
        gA += 64; gB += 64;
        __syncthreads();

#pragma unroll
        for (int s = 0; s < 2; ++s) {
            int xs = s ? x1 : x0;
            short8 af[4], bfr[4];
#pragma unroll
            for (int mi = 0; mi < 4; ++mi)
                af[mi] = *(const short8*)(As + (wr * 64 + mi * 16 + m) * 128 + xs);
#pragma unroll
            for (int ni = 0; ni < 4; ++ni)
                bfr[ni] = *(const short8*)(Bs + (wc * 64 + ni * 16 + m) * 128 + xs);
#pragma unroll
            for (int mi = 0; mi < 4; ++mi)
#pragma unroll
                for (int ni = 0; ni < 4; ++ni)
                    acc[mi][ni] = __builtin_amdgcn_mfma_f32_16x16x32_bf16(
                        af[mi], bfr[ni], acc[mi][ni], 0, 0, 0);
        }
        __syncthreads();
    }

    // ---- epilogue: transpose through LDS, coalesced bf16 stores ----
    unsigned short* T = (unsigned short*)smem;  // [128][136]
#pragma unroll
    for (int mi = 0; mi < 4; ++mi) {
        int row = wr * 64 + mi * 16 + q * 4;       // node-local (4 consecutive)
#pragma unroll
        for (int ni = 0; ni < 4; ++ni) {
            int col = wc * 64 + ni * 16 + m;       // f-local
            float bv = bias[n0 + col];
            ushortx4 pk;
#pragma unroll
            for (int r = 0; r < 4; ++r) pk[r] = f2bf(acc[mi][ni][r] + bv);
            *(ushortx4*)(T + col * 136 + row) = pk;
        }
    }
    __syncthreads();
    int f  = t >> 1;             // 0..127
    int c0 = (t & 1) * 64;       // node half
    int bb = m0 >> 11;
    int node0 = (m0 & 2047) + c0;
    unsigned short* dst = XwT + ((size_t)bb * FOUT_ + n0 + f) * N_ + node0;
    const unsigned short* src = T + f * 136 + c0;
#pragma unroll
    for (int u = 0; u < 8; ++u)
        *(ushortx8*)(dst + u * 8) = *(const ushortx8*)(src + u * 8);
}

// --- 5) GEMM2: out[b] = Lbf[b] @ x[b], 64x128 tile, BK=64, 32 iters ---------
__global__ __launch_bounds__(256) void gemm2_kernel(
    const unsigned short* __restrict__ Lbf,   // [8][2048][2048]
    const unsigned short* __restrict__ XwT,   // [8][512][2048]  (= x^T = B^T)
    float* __restrict__ out) {                // [8][2048][512]
    __shared__ __align__(16) char smem[24576];
    char* As = smem;            // 64 x 128 B (swizzled) = 8 KB
    char* Bs = smem + 8192;     // 128 x 128 B (swizzled) = 16 KB

    int t = threadIdx.x;
    int lane = t & 63;
    int wave = t >> 6;
    int wr = wave & 1;        // 2 row-groups of 32
    int wc = wave >> 1;       // 2 col-groups of 64
    int q = lane >> 4, m = lane & 15;
    int n0 = blockIdx.x * 128;   // FOUT block
    int m0 = blockIdx.y * 64;    // node block
    int b = blockIdx.z;
    const unsigned short* Ab = Lbf + (size_t)b * N_ * N_;
    const unsigned short* Bb = XwT + (size_t)b * FOUT_ * N_;

    int srow = t >> 3;
    int scol = (((t & 7) ^ (srow & 7)) * 8);
    int x0 = ((q ^ (m & 7)) * 16);
    int x1 = x0 ^ 64;

    floatx4 acc[2][4];
#pragma unroll
    for (int mi = 0; mi < 2; ++mi)
#pragma unroll
        for (int ni = 0; ni < 4; ++ni)
            acc[mi][ni] = (floatx4){0.f, 0.f, 0.f, 0.f};

    const unsigned short* gA = Ab + (size_t)(m0 + srow) * N_ + scol;
    const unsigned short* gB = Bb + (size_t)(n0 + srow) * N_ + scol;
    char* lA = As + wave * 1024;
    char* lB = Bs + wave * 1024;

    for (int kt = 0; kt < N_ / 64; ++kt) {
#pragma unroll
        for (int u = 0; u < 2; ++u)
            glds16(gA + (size_t)(u * 32) * N_, lA + u * 4096);
#pragma unroll
        for (int u = 0; u < 4; ++u)
            glds16(gB + (size_t)(u * 32) * N_, lB + u * 4096);
        gA += 64; gB += 64;
        __syncthreads();

#pragma unroll
        for (int s = 0; s < 2; ++s) {
            int xs = s ? x1 : x0;
            short8 af[2], bfr[4];
#pragma unroll
            for (int mi = 0; mi < 2; ++mi)
                af[mi] = *(const short8*)(As + (wr * 32 + mi * 16 + m) * 128 + xs);
#pragma unroll
            for (int ni = 0; ni < 4; ++ni)
                bfr[ni] = *(const short8*)(Bs + (wc * 64 + ni * 16 + m) * 128 + xs);
#pragma unroll
            for (int mi = 0; mi < 2; ++mi)
#pragma unroll
                for (int ni = 0; ni < 4; ++ni)
                    acc[mi][ni] = __builtin_amdgcn_mfma_f32_16x16x32_bf16(
                        af[mi], bfr[ni], acc[mi][ni], 0, 0, 0);
        }
        __syncthreads();
    }

    // C/D layout: col = lane&15, row = (lane>>4)*4 + reg
    float* C = out + (size_t)b * N_ * FOUT_;
#pragma unroll
    for (int mi = 0; mi < 2; ++mi) {
        int rowb = m0 + wr * 32 + mi * 16 + q * 4;
#pragma unroll
        for (int ni = 0; ni < 4; ++ni) {
            int col = n0 + wc * 64 + ni * 16 + m;
#pragma unroll
            for (int r = 0; r < 4; ++r)
                C[(size_t)(rowb + r) * FOUT_ + col] = acc[mi][ni][r];
        }
    }
}

extern "C" void kernel_launch(void* const* d_in, const int* in_sizes, int n_in,
                              void* d_out, int out_size, void* d_ws, size_t ws_size,
                              hipStream_t stream) {
    const float* X    = (const float*)d_in[0];   // [8,2048,512]
    const float* A    = (const float*)d_in[1];   // [8,2048,2048]
    const float* W    = (const float*)d_in[2];   // [512,512]
    const float* bias = (const float*)d_in[3];   // [512]
    float* out = (float*)d_out;                  // [8,2048,512] fp32
    char* ws = (char*)d_ws;

    float* dinv          = (float*)(ws);                              // 64 KB
    unsigned short* Xbf  = (unsigned short*)(ws + (1u << 16));        // 16 MB
    unsigned short* Wt   = (unsigned short*)(ws + (1u << 16) + 16777216u);           // 512 KB
    unsigned short* XwT  = (unsigned short*)(ws + (1u << 16) + 16777216u + 524288u); // 16 MB
    unsigned short* Lbf  = (unsigned short*)(ws + (1u << 16) + 16777216u + 524288u + 16777216u); // 64 MB

    degree_kernel<<<B_ * N_, 256, 0, stream>>>(A, dinv);
    scaleL_kernel<<<(B_ * (size_t)N_ * N_) / 2048, 256, 0, stream>>>(A, dinv, Lbf);
    castX_kernel<<<((size_t)B_ * N_ * FIN_) / 2048, 256, 0, stream>>>(X, Xbf);
    transposeW_kernel<<<dim3(FOUT_ / 32, FIN_ / 32), dim3(32, 8), 0, stream>>>(W, Wt);

    gemm1_kernel<<<dim3(FOUT_ / 128, (B_ * N_) / 128), 256, 0, stream>>>(
        Xbf, Wt, XwT, bias);

    gemm2_kernel<<<dim3(FOUT_ / 128, N_ / 64, B_), 256, 0, stream>>>(
        Lbf, XwT, out);
}

// Round 4
// 328.417 us; speedup vs baseline: 1.0492x; 1.0480x over previous
//
#include <hip/hip_runtime.h>

#define B_ 8
#define N_ 2048
#define FIN_ 512
#define FOUT_ 512

typedef __attribute__((ext_vector_type(8))) short short8;
typedef __attribute__((ext_vector_type(4))) float floatx4;
typedef __attribute__((ext_vector_type(4))) unsigned short ushortx4;
typedef __attribute__((ext_vector_type(8))) unsigned short ushortx8;

__device__ inline unsigned short f2bf(float f) {
    union { float f; unsigned int u; } x; x.f = f;
    unsigned int r = x.u + 0x7FFFu + ((x.u >> 16) & 1u);  // RNE
    return (unsigned short)(r >> 16);
}

__device__ inline void glds16(const void* g, void* l) {
    __builtin_amdgcn_global_load_lds(
        (const __attribute__((address_space(1))) void*)g,
        (__attribute__((address_space(3))) void*)l, 16, 0, 0);
}

// --- 1) dinv[b*N+i] = rsqrt(1 + sum_j A[b,i,j]) ------------------------------
__global__ __launch_bounds__(256) void degree_kernel(const float* __restrict__ A,
                                                     float* __restrict__ dinv) {
    int row = blockIdx.x;                 // b*N + i
    const float4* A4 = (const float4*)(A + (size_t)row * N_);
    int t = threadIdx.x;
    float4 v0 = A4[t];
    float4 v1 = A4[t + 256];
    float s = v0.x + v0.y + v0.z + v0.w + v1.x + v1.y + v1.z + v1.w;
#pragma unroll
    for (int off = 32; off > 0; off >>= 1) s += __shfl_down(s, off, 64);
    __shared__ float red[4];
    if ((t & 63) == 0) red[t >> 6] = s;
    __syncthreads();
    if (t == 0) dinv[row] = rsqrtf(red[0] + red[1] + red[2] + red[3] + 1.0f);
}

// --- 2) Lbf[b,i,j] = bf16((A[b,i,j] + (i==j)) * dinv_i * dinv_j) -------------
__global__ __launch_bounds__(256) void scaleL_kernel(const float* __restrict__ A,
                                                     const float* __restrict__ dinv,
                                                     unsigned short* __restrict__ Lbf) {
    size_t e0 = ((size_t)blockIdx.x * 256 + threadIdx.x) * 8;
    int b   = (int)(e0 >> 22);            // N*N = 2^22
    int rem = (int)(e0 & ((1u << 22) - 1));
    int i   = rem >> 11;                  // N = 2^11
    int j0  = rem & 2047;
    float di = dinv[b * N_ + i];
    const float* dj = dinv + b * N_ + j0;
    float4 a0 = *(const float4*)(A + e0);
    float4 a1 = *(const float4*)(A + e0 + 4);
    float4 d0 = *(const float4*)(dj);
    float4 d1 = *(const float4*)(dj + 4);
    float av[8] = {a0.x, a0.y, a0.z, a0.w, a1.x, a1.y, a1.z, a1.w};
    float dv[8] = {d0.x, d0.y, d0.z, d0.w, d1.x, d1.y, d1.z, d1.w};
    int dd = i - j0;
    if (dd >= 0 && dd < 8) av[dd] += 1.0f;
    ushortx8 p;
#pragma unroll
    for (int r = 0; r < 8; ++r) p[r] = f2bf(av[r] * di * dv[r]);
    *(ushortx8*)(Lbf + e0) = p;
}

// --- 3a) X -> bf16 -----------------------------------------------------------
__global__ __launch_bounds__(256) void castX_kernel(const float* __restrict__ X,
                                                    unsigned short* __restrict__ Xbf) {
    size_t e0 = ((size_t)blockIdx.x * 256 + threadIdx.x) * 8;
    float4 a0 = *(const float4*)(X + e0);
    float4 a1 = *(const float4*)(X + e0 + 4);
    float av[8] = {a0.x, a0.y, a0.z, a0.w, a1.x, a1.y, a1.z, a1.w};
    ushortx8 p;
#pragma unroll
    for (int r = 0; r < 8; ++r) p[r] = f2bf(av[r]);
    *(ushortx8*)(Xbf + e0) = p;
}

// --- 3b) Wt[n][k] = bf16(W[k][n]) -------------------------------------------
__global__ __launch_bounds__(256) void transposeW_kernel(const float* __restrict__ W,
                                                         unsigned short* __restrict__ Wt) {
    __shared__ float tile[32][33];
    int bx = blockIdx.x * 32;   // F_OUT block
    int by = blockIdx.y * 32;   // F_IN block
    int tx = threadIdx.x, ty = threadIdx.y;   // 32 x 8
#pragma unroll
    for (int r = 0; r < 32; r += 8)
        tile[ty + r][tx] = W[(size_t)(by + ty + r) * FOUT_ + bx + tx];
    __syncthreads();
#pragma unroll
    for (int r = 0; r < 32; r += 8)
        Wt[(size_t)(bx + ty + r) * FIN_ + by + tx] = f2bf(tile[tx][ty + r]);
}

// ============================================================================
// Swizzled LDS tile: rows of BK=64 bf16 (128 B = 8 chunks of 16 B).
// chunk' = chunk ^ (row & 7).  Staging thread t of issue u lands at flat byte
// u*4096 + t*16 -> row = u*32 + (t>>3), chunk' = t&7, so it fetches global
// chunk c = (t&7) ^ ((t>>3)&7).  Fragment reads: 2-way bank alias (free).
// Verified round 3: SQ_LDS_BANK_CONFLICT = 0.
// ============================================================================

// --- 4) GEMM1: x^T = (Xbf @ Wt^T + b)^T, 128x128 tile, BK=64, 8 iters -------
__global__ __launch_bounds__(256) void gemm1_kernel(
    const unsigned short* __restrict__ Abase,   // Xbf [16384][512]
    const unsigned short* __restrict__ Btbase,  // Wt  [512][512]
    unsigned short* __restrict__ XwT,           // [8][512][2048]
    const float* __restrict__ bias) {
    __shared__ __align__(16) char smem[34816];  // K-loop 32 KB; epi 128x136 bf16
    char* As = smem;            // 128 x 128 B (swizzled) = 16 KB
    char* Bs = smem + 16384;    // 128 x 128 B (swizzled) = 16 KB

    int t = threadIdx.x;
    int lane = t & 63;
    int wave = t >> 6;
    int wr = wave >> 1, wc = wave & 1;
    int q = lane >> 4, m = lane & 15;
    int n0 = blockIdx.x * 128;   // FOUT block
    int m0 = blockIdx.y * 128;   // node block

    int srow = t >> 3;                       // 0..31 per issue
    int scol = (((t & 7) ^ (srow & 7)) * 8); // global elem chunk start
    int x0 = ((q ^ (m & 7)) * 16);           // sub-slab 0 chunk byte
    int x1 = x0 ^ 64;                        // sub-slab 1

    floatx4 acc[4][4];
#pragma unroll
    for (int mi = 0; mi < 4; ++mi)
#pragma unroll
        for (int ni = 0; ni < 4; ++ni)
            acc[mi][ni] = (floatx4){0.f, 0.f, 0.f, 0.f};

    const unsigned short* gA = Abase + (size_t)(m0 + srow) * FIN_ + scol;
    const unsigned short* gB = Btbase + (size_t)(n0 + srow) * FIN_ + scol;
    char* lA = As + wave * 1024;
    char* lB = Bs + wave * 1024;

    for (int kt = 0; kt < FIN_ / 64; ++kt) {
#pragma unroll
        for (int u = 0; u < 4; ++u) {
            glds16(gA + (size_t)(u * 32) * FIN_, lA + u * 4096);
            glds16(gB + (size_t)(u * 32) * FIN_, lB + u * 4096);
        }
        gA += 64; gB += 64;
        __syncthreads();

#pragma unroll
        for (int sl = 0; sl < 2; ++sl) {
            int xs = sl ? x1 : x0;
            short8 af[4], bfr[4];
#pragma unroll
            for (int mi = 0; mi < 4; ++mi)
                af[mi] = *(const short8*)(As + (wr * 64 + mi * 16 + m) * 128 + xs);
#pragma unroll
            for (int ni = 0; ni < 4; ++ni)
                bfr[ni] = *(const short8*)(Bs + (wc * 64 + ni * 16 + m) * 128 + xs);
#pragma unroll
            for (int mi = 0; mi < 4; ++mi)
#pragma unroll
                for (int ni = 0; ni < 4; ++ni)
                    acc[mi][ni] = __builtin_amdgcn_mfma_f32_16x16x32_bf16(
                        af[mi], bfr[ni], acc[mi][ni], 0, 0, 0);
        }
        __syncthreads();
    }

    // ---- epilogue: transpose through LDS, coalesced bf16 stores ----
    unsigned short* T = (unsigned short*)smem;  // [128][136]
#pragma unroll
    for (int mi = 0; mi < 4; ++mi) {
        int row = wr * 64 + mi * 16 + q * 4;       // node-local (4 consecutive)
#pragma unroll
        for (int ni = 0; ni < 4; ++ni) {
            int col = wc * 64 + ni * 16 + m;       // f-local
            float bv = bias[n0 + col];
            ushortx4 pk;
#pragma unroll
            for (int r = 0; r < 4; ++r) pk[r] = f2bf(acc[mi][ni][r] + bv);
            *(ushortx4*)(T + col * 136 + row) = pk;
        }
    }
    __syncthreads();
    int f  = t >> 1;             // 0..127
    int c0 = (t & 1) * 64;       // node half
    int bb = m0 >> 11;
    int node0 = (m0 & 2047) + c0;
    unsigned short* dst = XwT + ((size_t)bb * FOUT_ + n0 + f) * N_ + node0;
    const unsigned short* src = T + f * 136 + c0;
#pragma unroll
    for (int u = 0; u < 8; ++u)
        *(ushortx8*)(dst + u * 8) = *(const ushortx8*)(src + u * 8);
}

// --- 5) GEMM2: out[b] = Lbf[b] @ x[b] ---------------------------------------
// 128x128 tile (m97 LDS:MFMA ratio 1.24), BK=64, 32 iters, swizzled LDS.
// XCD-aware 1D grid: batch = id & 7 (pins batch b to XCD b under id%8
// round-robin); within an XCD the 4 n-siblings of one m-tile are adjacent
// in dispatch order so L2 serves 3 of the 4 Lbf-tile reads.
__global__ __launch_bounds__(256) void gemm2_kernel(
    const unsigned short* __restrict__ Lbf,   // [8][2048][2048]
    const unsigned short* __restrict__ XwT,   // [8][512][2048]  (= x^T = B^T)
    float* __restrict__ out) {                // [8][2048][512]
    __shared__ __align__(16) char smem[32768];
    char* As = smem;            // 128 x 128 B (swizzled) = 16 KB
    char* Bs = smem + 16384;    // 128 x 128 B (swizzled) = 16 KB

    int t = threadIdx.x;
    int lane = t & 63;
    int wave = t >> 6;
    int wr = wave >> 1, wc = wave & 1;
    int q = lane >> 4, m = lane & 15;

    int id = blockIdx.x;
    int b  = id & 7;             // XCD pin
    int s  = id >> 3;            // 0..63 within batch
    int n0 = (s & 3) * 128;      // n-siblings adjacent in time
    int m0 = (s >> 2) * 128;

    const unsigned short* Ab = Lbf + (size_t)b * N_ * N_;
    const unsigned short* Bb = XwT + (size_t)b * FOUT_ * N_;

    int srow = t >> 3;
    int scol = (((t & 7) ^ (srow & 7)) * 8);
    int x0 = ((q ^ (m & 7)) * 16);
    int x1 = x0 ^ 64;

    floatx4 acc[4][4];
#pragma unroll
    for (int mi = 0; mi < 4; ++mi)
#pragma unroll
        for (int ni = 0; ni < 4; ++ni)
            acc[mi][ni] = (floatx4){0.f, 0.f, 0.f, 0.f};

    const unsigned short* gA = Ab + (size_t)(m0 + srow) * N_ + scol;
    const unsigned short* gB = Bb + (size_t)(n0 + srow) * N_ + scol;
    char* lA = As + wave * 1024;
    char* lB = Bs + wave * 1024;

    for (int kt = 0; kt < N_ / 64; ++kt) {
#pragma unroll
        for (int u = 0; u < 4; ++u) {
            glds16(gA + (size_t)(u * 32) * N_, lA + u * 4096);
            glds16(gB + (size_t)(u * 32) * N_, lB + u * 4096);
        }
        gA += 64; gB += 64;
        __syncthreads();

#pragma unroll
        for (int sl = 0; sl < 2; ++sl) {
            int xs = sl ? x1 : x0;
            short8 af[4], bfr[4];
#pragma unroll
            for (int mi = 0; mi < 4; ++mi)
                af[mi] = *(const short8*)(As + (wr * 64 + mi * 16 + m) * 128 + xs);
#pragma unroll
            for (int ni = 0; ni < 4; ++ni)
                bfr[ni] = *(const short8*)(Bs + (wc * 64 + ni * 16 + m) * 128 + xs);
#pragma unroll
            for (int mi = 0; mi < 4; ++mi)
#pragma unroll
                for (int ni = 0; ni < 4; ++ni)
                    acc[mi][ni] = __builtin_amdgcn_mfma_f32_16x16x32_bf16(
                        af[mi], bfr[ni], acc[mi][ni], 0, 0, 0);
        }
        __syncthreads();
    }

    // C/D layout: col = lane&15, row = (lane>>4)*4 + reg
    float* C = out + (size_t)b * N_ * FOUT_;
#pragma unroll
    for (int mi = 0; mi < 4; ++mi) {
        int rowb = m0 + wr * 64 + mi * 16 + q * 4;
#pragma unroll
        for (int ni = 0; ni < 4; ++ni) {
            int col = n0 + wc * 64 + ni * 16 + m;
#pragma unroll
            for (int r = 0; r < 4; ++r)
                C[(size_t)(rowb + r) * FOUT_ + col] = acc[mi][ni][r];
        }
    }
}

extern "C" void kernel_launch(void* const* d_in, const int* in_sizes, int n_in,
                              void* d_out, int out_size, void* d_ws, size_t ws_size,
                              hipStream_t stream) {
    const float* X    = (const float*)d_in[0];   // [8,2048,512]
    const float* A    = (const float*)d_in[1];   // [8,2048,2048]
    const float* W    = (const float*)d_in[2];   // [512,512]
    const float* bias = (const float*)d_in[3];   // [512]
    float* out = (float*)d_out;                  // [8,2048,512] fp32
    char* ws = (char*)d_ws;

    float* dinv          = (float*)(ws);                              // 64 KB
    unsigned short* Xbf  = (unsigned short*)(ws + (1u << 16));        // 16 MB
    unsigned short* Wt   = (unsigned short*)(ws + (1u << 16) + 16777216u);           // 512 KB
    unsigned short* XwT  = (unsigned short*)(ws + (1u << 16) + 16777216u + 524288u); // 16 MB
    unsigned short* Lbf  = (unsigned short*)(ws + (1u << 16) + 16777216u + 524288u + 16777216u); // 64 MB

    degree_kernel<<<B_ * N_, 256, 0, stream>>>(A, dinv);
    scaleL_kernel<<<(B_ * (size_t)N_ * N_) / 2048, 256, 0, stream>>>(A, dinv, Lbf);
    castX_kernel<<<((size_t)B_ * N_ * FIN_) / 2048, 256, 0, stream>>>(X, Xbf);
    transposeW_kernel<<<dim3(FOUT_ / 32, FIN_ / 32), dim3(32, 8), 0, stream>>>(W, Wt);

    gemm1_kernel<<<dim3(FOUT_ / 128, (B_ * N_) / 128), 256, 0, stream>>>(
        Xbf, Wt, XwT, bias);

    gemm2_kernel<<<512, 256, 0, stream>>>(Lbf, XwT, out);
}

// Round 5
// 289.118 us; speedup vs baseline: 1.1919x; 1.1359x over previous
//
#include <hip/hip_runtime.h>

#define B_ 8
#define N_ 2048
#define FIN_ 512
#define FOUT_ 512

typedef __attribute__((ext_vector_type(8))) short short8;
typedef __attribute__((ext_vector_type(4))) float floatx4;
typedef __attribute__((ext_vector_type(4))) unsigned short ushortx4;
typedef __attribute__((ext_vector_type(8))) unsigned short ushortx8;

__device__ inline unsigned short f2bf(float f) {
    union { float f; unsigned int u; } x; x.f = f;
    unsigned int r = x.u + 0x7FFFu + ((x.u >> 16) & 1u);  // RNE
    return (unsigned short)(r >> 16);
}

__device__ inline void glds16(const void* g, void* l) {
    __builtin_amdgcn_global_load_lds(
        (const __attribute__((address_space(1))) void*)g,
        (__attribute__((address_space(3))) void*)l, 16, 0, 0);
}

// --- 1) Fused: dinv[b*N+i] = rsqrt(1 + sum_j A[b,i,j]);  Abf = bf16(A) ------
// One streaming pass over A (134 MB read + 67 MB write).
__global__ __launch_bounds__(256) void degree_cast_kernel(
    const float* __restrict__ A, float* __restrict__ dinv,
    unsigned short* __restrict__ Abf) {
    int row = blockIdx.x;                 // b*N + i
    size_t base = (size_t)row * N_;
    const float4* A4 = (const float4*)(A + base);
    int t = threadIdx.x;
    float4 v0 = A4[t];
    float4 v1 = A4[t + 256];
    ushortx4 p0, p1;
    p0[0] = f2bf(v0.x); p0[1] = f2bf(v0.y); p0[2] = f2bf(v0.z); p0[3] = f2bf(v0.w);
    p1[0] = f2bf(v1.x); p1[1] = f2bf(v1.y); p1[2] = f2bf(v1.z); p1[3] = f2bf(v1.w);
    *(ushortx4*)(Abf + base + t * 4) = p0;
    *(ushortx4*)(Abf + base + (t + 256) * 4) = p1;
    float s = v0.x + v0.y + v0.z + v0.w + v1.x + v1.y + v1.z + v1.w;
#pragma unroll
    for (int off = 32; off > 0; off >>= 1) s += __shfl_down(s, off, 64);
    __shared__ float red[4];
    if ((t & 63) == 0) red[t >> 6] = s;
    __syncthreads();
    if (t == 0) dinv[row] = rsqrtf(red[0] + red[1] + red[2] + red[3] + 1.0f);
}

// --- 2a) X -> bf16 -----------------------------------------------------------
__global__ __launch_bounds__(256) void castX_kernel(const float* __restrict__ X,
                                                    unsigned short* __restrict__ Xbf) {
    size_t e0 = ((size_t)blockIdx.x * 256 + threadIdx.x) * 8;
    float4 a0 = *(const float4*)(X + e0);
    float4 a1 = *(const float4*)(X + e0 + 4);
    float av[8] = {a0.x, a0.y, a0.z, a0.w, a1.x, a1.y, a1.z, a1.w};
    ushortx8 p;
#pragma unroll
    for (int r = 0; r < 8; ++r) p[r] = f2bf(av[r]);
    *(ushortx8*)(Xbf + e0) = p;
}

// --- 2b) Wt[n][k] = bf16(W[k][n]) -------------------------------------------
__global__ __launch_bounds__(256) void transposeW_kernel(const float* __restrict__ W,
                                                         unsigned short* __restrict__ Wt) {
    __shared__ float tile[32][33];
    int bx = blockIdx.x * 32;   // F_OUT block
    int by = blockIdx.y * 32;   // F_IN block
    int tx = threadIdx.x, ty = threadIdx.y;   // 32 x 8
#pragma unroll
    for (int r = 0; r < 32; r += 8)
        tile[ty + r][tx] = W[(size_t)(by + ty + r) * FOUT_ + bx + tx];
    __syncthreads();
#pragma unroll
    for (int r = 0; r < 32; r += 8)
        Wt[(size_t)(bx + ty + r) * FIN_ + by + tx] = f2bf(tile[tx][ty + r]);
}

// ============================================================================
// Swizzled LDS tile: rows of BK=64 bf16 (128 B = 8 chunks of 16 B).
// chunk' = chunk ^ (row & 7).  Staging thread t of issue u lands at flat byte
// u*4096 + t*16 -> row = u*32 + (t>>3), chunk' = t&7, so it fetches global
// chunk c = (t&7) ^ ((t>>3)&7).  Fragment reads: 2-way bank alias (free).
// Verified round 3: SQ_LDS_BANK_CONFLICT = 0.
// ============================================================================

// --- 3) GEMM1: y^T = ((Xbf @ Wt^T + b) * d_node)^T, 128x128 tile, BK=64 -----
__global__ __launch_bounds__(256) void gemm1_kernel(
    const unsigned short* __restrict__ Abase,   // Xbf [16384][512]
    const unsigned short* __restrict__ Btbase,  // Wt  [512][512]
    unsigned short* __restrict__ XwT,           // [8][512][2048]  (= y^T)
    const float* __restrict__ bias,
    const float* __restrict__ dinv) {           // [16384]
    __shared__ __align__(16) char smem[34816];  // K-loop 32 KB; epi 128x136 bf16
    char* As = smem;            // 128 x 128 B (swizzled) = 16 KB
    char* Bs = smem + 16384;    // 128 x 128 B (swizzled) = 16 KB

    int t = threadIdx.x;
    int lane = t & 63;
    int wave = t >> 6;
    int wr = wave >> 1, wc = wave & 1;
    int q = lane >> 4, m = lane & 15;
    int n0 = blockIdx.x * 128;   // FOUT block
    int m0 = blockIdx.y * 128;   // node block (flat b*N+node)

    int srow = t >> 3;                       // 0..31 per issue
    int scol = (((t & 7) ^ (srow & 7)) * 8); // global elem chunk start
    int x0 = ((q ^ (m & 7)) * 16);           // sub-slab 0 chunk byte
    int x1 = x0 ^ 64;                        // sub-slab 1

    floatx4 acc[4][4];
#pragma unroll
    for (int mi = 0; mi < 4; ++mi)
#pragma unroll
        for (int ni = 0; ni < 4; ++ni)
            acc[mi][ni] = (floatx4){0.f, 0.f, 0.f, 0.f};

    const unsigned short* gA = Abase + (size_t)(m0 + srow) * FIN_ + scol;
    const unsigned short* gB = Btbase + (size_t)(n0 + srow) * FIN_ + scol;
    char* lA = As + wave * 1024;
    char* lB = Bs + wave * 1024;

    for (int kt = 0; kt < FIN_ / 64; ++kt) {
#pragma unroll
        for (int u = 0; u < 4; ++u) {
            glds16(gA + (size_t)(u * 32) * FIN_, lA + u * 4096);
            glds16(gB + (size_t)(u * 32) * FIN_, lB + u * 4096);
        }
        gA += 64; gB += 64;
        __syncthreads();

#pragma unroll
        for (int sl = 0; sl < 2; ++sl) {
            int xs = sl ? x1 : x0;
            short8 af[4], bfr[4];
#pragma unroll
            for (int mi = 0; mi < 4; ++mi)
                af[mi] = *(const short8*)(As + (wr * 64 + mi * 16 + m) * 128 + xs);
#pragma unroll
            for (int ni = 0; ni < 4; ++ni)
                bfr[ni] = *(const short8*)(Bs + (wc * 64 + ni * 16 + m) * 128 + xs);
#pragma unroll
            for (int mi = 0; mi < 4; ++mi)
#pragma unroll
                for (int ni = 0; ni < 4; ++ni)
                    acc[mi][ni] = __builtin_amdgcn_mfma_f32_16x16x32_bf16(
                        af[mi], bfr[ni], acc[mi][ni], 0, 0, 0);
        }
        __syncthreads();
    }

    // ---- epilogue: (acc + bias) * dinv_node, transpose via LDS, store ------
    unsigned short* T = (unsigned short*)smem;  // [128][136]
#pragma unroll
    for (int mi = 0; mi < 4; ++mi) {
        int row = wr * 64 + mi * 16 + q * 4;       // node-local (4 consecutive)
        float4 dv = *(const float4*)(dinv + m0 + row);
        float dr[4] = {dv.x, dv.y, dv.z, dv.w};
#pragma unroll
        for (int ni = 0; ni < 4; ++ni) {
            int col = wc * 64 + ni * 16 + m;       // f-local
            float bv = bias[n0 + col];
            ushortx4 pk;
#pragma unroll
            for (int r = 0; r < 4; ++r) pk[r] = f2bf((acc[mi][ni][r] + bv) * dr[r]);
            *(ushortx4*)(T + col * 136 + row) = pk;
        }
    }
    __syncthreads();
    int f  = t >> 1;             // 0..127
    int c0 = (t & 1) * 64;       // node half
    int bb = m0 >> 11;
    int node0 = (m0 & 2047) + c0;
    unsigned short* dst = XwT + ((size_t)bb * FOUT_ + n0 + f) * N_ + node0;
    const unsigned short* src = T + f * 136 + c0;
#pragma unroll
    for (int u = 0; u < 8; ++u)
        *(ushortx8*)(dst + u * 8) = *(const ushortx8*)(src + u * 8);
}

// --- 4) GEMM2: out[b,i,:] = d_i * (Abf[b,i,:] @ y[b] + y[b,i,:]) ------------
// 128x128 tile, BK=64, swizzled LDS, XCD-aware 1D grid (batch = id & 7).
__global__ __launch_bounds__(256) void gemm2_kernel(
    const unsigned short* __restrict__ Abf,   // [8][2048][2048] raw bf16(A)
    const unsigned short* __restrict__ XwT,   // [8][512][2048]  (= y^T = B^T)
    const float* __restrict__ dinv,           // [16384]
    float* __restrict__ out) {                // [8][2048][512]
    __shared__ __align__(16) char smem[32768];
    char* As = smem;            // 128 x 128 B (swizzled) = 16 KB
    char* Bs = smem + 16384;    // 128 x 128 B (swizzled) = 16 KB

    int t = threadIdx.x;
    int lane = t & 63;
    int wave = t >> 6;
    int wr = wave >> 1, wc = wave & 1;
    int q = lane >> 4, m = lane & 15;

    int id = blockIdx.x;
    int b  = id & 7;             // XCD pin
    int s  = id >> 3;            // 0..63 within batch
    int n0 = (s & 3) * 128;      // n-siblings adjacent in time
    int m0 = (s >> 2) * 128;

    const unsigned short* Ab = Abf + (size_t)b * N_ * N_;
    const unsigned short* Bb = XwT + (size_t)b * FOUT_ * N_;

    int srow = t >> 3;
    int scol = (((t & 7) ^ (srow & 7)) * 8);
    int x0 = ((q ^ (m & 7)) * 16);
    int x1 = x0 ^ 64;

    floatx4 acc[4][4];
#pragma unroll
    for (int mi = 0; mi < 4; ++mi)
#pragma unroll
        for (int ni = 0; ni < 4; ++ni)
            acc[mi][ni] = (floatx4){0.f, 0.f, 0.f, 0.f};

    const unsigned short* gA = Ab + (size_t)(m0 + srow) * N_ + scol;
    const unsigned short* gB = Bb + (size_t)(n0 + srow) * N_ + scol;
    char* lA = As + wave * 1024;
    char* lB = Bs + wave * 1024;

    for (int kt = 0; kt < N_ / 64; ++kt) {
#pragma unroll
        for (int u = 0; u < 4; ++u) {
            glds16(gA + (size_t)(u * 32) * N_, lA + u * 4096);
            glds16(gB + (size_t)(u * 32) * N_, lB + u * 4096);
        }
        gA += 64; gB += 64;
        __syncthreads();

#pragma unroll
        for (int sl = 0; sl < 2; ++sl) {
            int xs = sl ? x1 : x0;
            short8 af[4], bfr[4];
#pragma unroll
            for (int mi = 0; mi < 4; ++mi)
                af[mi] = *(const short8*)(As + (wr * 64 + mi * 16 + m) * 128 + xs);
#pragma unroll
            for (int ni = 0; ni < 4; ++ni)
                bfr[ni] = *(const short8*)(Bs + (wc * 64 + ni * 16 + m) * 128 + xs);
#pragma unroll
            for (int mi = 0; mi < 4; ++mi)
#pragma unroll
                for (int ni = 0; ni < 4; ++ni)
                    acc[mi][ni] = __builtin_amdgcn_mfma_f32_16x16x32_bf16(
                        af[mi], bfr[ni], acc[mi][ni], 0, 0, 0);
        }
        __syncthreads();
    }

    // C/D layout: col = lane&15, row = (lane>>4)*4 + reg
    // out_row = d_row * (acc_row + y_row[col]),  y = XwT[b][col][row] (bf16)
    float* C = out + (size_t)b * N_ * FOUT_;
#pragma unroll
    for (int mi = 0; mi < 4; ++mi) {
        int rowb = m0 + wr * 64 + mi * 16 + q * 4;
        float4 dv = *(const float4*)(dinv + b * N_ + rowb);
        float dr[4] = {dv.x, dv.y, dv.z, dv.w};
#pragma unroll
        for (int ni = 0; ni < 4; ++ni) {
            int col = n0 + wc * 64 + ni * 16 + m;
            ushortx4 yv = *(const ushortx4*)(Bb + (size_t)col * N_ + rowb);
#pragma unroll
            for (int r = 0; r < 4; ++r) {
                union { unsigned int u; float f; } yc; yc.u = ((unsigned int)yv[r]) << 16;
                C[(size_t)(rowb + r) * FOUT_ + col] = dr[r] * (acc[mi][ni][r] + yc.f);
            }
        }
    }
}

extern "C" void kernel_launch(void* const* d_in, const int* in_sizes, int n_in,
                              void* d_out, int out_size, void* d_ws, size_t ws_size,
                              hipStream_t stream) {
    const float* X    = (const float*)d_in[0];   // [8,2048,512]
    const float* A    = (const float*)d_in[1];   // [8,2048,2048]
    const float* W    = (const float*)d_in[2];   // [512,512]
    const float* bias = (const float*)d_in[3];   // [512]
    float* out = (float*)d_out;                  // [8,2048,512] fp32
    char* ws = (char*)d_ws;

    float* dinv          = (float*)(ws);                              // 64 KB
    unsigned short* Xbf  = (unsigned short*)(ws + (1u << 16));        // 16 MB
    unsigned short* Wt   = (unsigned short*)(ws + (1u << 16) + 16777216u);           // 512 KB
    unsigned short* XwT  = (unsigned short*)(ws + (1u << 16) + 16777216u + 524288u); // 16 MB
    unsigned short* Abf  = (unsigned short*)(ws + (1u << 16) + 16777216u + 524288u + 16777216u); // 64 MB

    degree_cast_kernel<<<B_ * N_, 256, 0, stream>>>(A, dinv, Abf);
    castX_kernel<<<((size_t)B_ * N_ * FIN_) / 2048, 256, 0, stream>>>(X, Xbf);
    transposeW_kernel<<<dim3(FOUT_ / 32, FIN_ / 32), dim3(32, 8), 0, stream>>>(W, Wt);

    gemm1_kernel<<<dim3(FOUT_ / 128, (B_ * N_) / 128), 256, 0, stream>>>(
        Xbf, Wt, XwT, bias, dinv);

    gemm2_kernel<<<512, 256, 0, stream>>>(Abf, XwT, dinv, out);
}